// Round 3
// baseline (148.826 us; speedup 1.0000x reference)
//
#include <hip/hip_runtime.h>
#include <math.h>

#define B 128
#define E 6
#define IN_DIM 1664
#define H_DIM 512
#define OUT_DIM 618
#define ZD 32
#define K2 (H_DIM + ZD)   // 544

// ---------------------------------------------------------------------------
// Partial GEMM v3:
//   part[split][b][n] = sum_e sum_{k in chunk} x[b,k] * coef[b,e] * w[e,k,n]
// Block: 256 threads, tile = 128 rows x 32 cols. K-step outer (8 k's), experts
// inner. x lives in registers (per-thread rows, 8-lane broadcast loads);
// coef in registers; only w goes through LDS, staged for ALL 6 experts at
// once (6KB) -> one barrier pair per k-step (not per expert) and 1 ds_read
// per 20 VALU. Next k-step's w tile is prefetched into regs before compute
// (T14): HBM latency hides under the FMA loop. Non-atomic partial stores.
// ---------------------------------------------------------------------------
template<bool ALIGN4>
__global__ __launch_bounds__(256) void moe_gemm(
    const float* __restrict__ x,     // [B,K]
    const float* __restrict__ coef,  // [B,E]
    const float* __restrict__ w,     // [E,K,N]
    float* __restrict__ part,        // [S][B,N]
    int K, int N, int kchunk)        // kchunk % 8 == 0, divides K
{
    const int n0 = blockIdx.x * 32;
    const int k0 = blockIdx.y * kchunk;
    const int tid = threadIdx.x;
    const int tx = tid & 7;          // 8 column groups of 4 cols
    const int ty = tid >> 3;         // 32 row groups of 4 rows
    const int row0 = ty * 4;
    const int col0 = n0 + tx * 4;

    __shared__ float w_s[E * 8 * 32];   // [e][kk][n] flat, 6 KB

    // coef for this thread's 4 output rows, all experts (24 regs)
    float ce[4][E];
    #pragma unroll
    for (int i = 0; i < 4; ++i)
        #pragma unroll
        for (int e = 0; e < E; ++e)
            ce[i][e] = coef[(row0 + i) * E + e];

    float r[4][4];
    #pragma unroll
    for (int i = 0; i < 4; ++i)
        #pragma unroll
        for (int j = 0; j < 4; ++j) r[i][j] = 0.f;

    // ---- w tile load/store helpers (reg <-> global / LDS) ----
    // flat float index within tile: e*256 + kk*32 + n  (6*8*32 = 1536 floats)
    auto load_w = [&](int kb, float4* v4, float* vs) {
        if constexpr (ALIGN4) {
            {
                const int f = tid;                       // float4 index
                const int e = f >> 6, kk = (f >> 3) & 7, n4 = (f & 7) << 2;
                v4[0] = *reinterpret_cast<const float4*>(
                    w + ((size_t)e * K + kb + kk) * N + n0 + n4);
            }
            if (tid < 128) {
                const int f = 256 + tid;
                const int e = f >> 6, kk = (f >> 3) & 7, n4 = (f & 7) << 2;
                v4[1] = *reinterpret_cast<const float4*>(
                    w + ((size_t)e * K + kb + kk) * N + n0 + n4);
            }
        } else {
            #pragma unroll
            for (int i = 0; i < 6; ++i) {
                const int s = tid + i * 256;             // scalar index
                const int e = s >> 8, kk = (s >> 5) & 7, n = s & 31;
                const int col = n0 + n;
                vs[i] = (col < N) ? w[((size_t)e * K + kb + kk) * N + col] : 0.f;
            }
        }
    };
    auto store_w = [&](const float4* v4, const float* vs) {
        if constexpr (ALIGN4) {
            *reinterpret_cast<float4*>(&w_s[tid * 4]) = v4[0];
            if (tid < 128)
                *reinterpret_cast<float4*>(&w_s[1024 + tid * 4]) = v4[1];
        } else {
            #pragma unroll
            for (int i = 0; i < 6; ++i)
                w_s[tid + i * 256] = vs[i];
        }
    };

    const int nkb = kchunk >> 3;
    float4 wA4[2]; float wAs[6];
    load_w(k0, wA4, wAs);

    for (int kbi = 0; kbi < nkb; ++kbi) {
        const int kb = k0 + kbi * 8;

        // x -> regs (issued early; first use is after the 2nd barrier)
        float xrf[4][8];
        #pragma unroll
        for (int i = 0; i < 4; ++i) {
            const float* xp = x + (size_t)(row0 + i) * K + kb;
            const float4 a = *reinterpret_cast<const float4*>(xp);
            const float4 b = *reinterpret_cast<const float4*>(xp + 4);
            xrf[i][0] = a.x; xrf[i][1] = a.y; xrf[i][2] = a.z; xrf[i][3] = a.w;
            xrf[i][4] = b.x; xrf[i][5] = b.y; xrf[i][6] = b.z; xrf[i][7] = b.w;
        }

        __syncthreads();                 // previous iter's w_s reads done
        store_w(wA4, wAs);
        float4 wB4[2]; float wBs[6];
        if (kbi + 1 < nkb) load_w(kb + 8, wB4, wBs);   // prefetch next
        __syncthreads();                 // w_s visible

        #pragma unroll
        for (int e = 0; e < E; ++e) {
            #pragma unroll
            for (int kk = 0; kk < 8; ++kk) {
                const float4 w4 = *reinterpret_cast<const float4*>(
                    &w_s[(e * 8 + kk) * 32 + tx * 4]);
                #pragma unroll
                for (int i = 0; i < 4; ++i) {
                    const float av = xrf[i][kk] * ce[i][e];
                    r[i][0] = fmaf(av, w4.x, r[i][0]);
                    r[i][1] = fmaf(av, w4.y, r[i][1]);
                    r[i][2] = fmaf(av, w4.z, r[i][2]);
                    r[i][3] = fmaf(av, w4.w, r[i][3]);
                }
            }
        }

        wA4[0] = wB4[0]; wA4[1] = wB4[1];
        #pragma unroll
        for (int i = 0; i < 6; ++i) wAs[i] = wBs[i];
    }

    float* pb = part + (size_t)blockIdx.y * B * N;
    #pragma unroll
    for (int i = 0; i < 4; ++i) {
        const int row = row0 + i;
        if (ALIGN4) {
            float4 t;
            t.x = r[i][0]; t.y = r[i][1]; t.z = r[i][2]; t.w = r[i][3];
            *reinterpret_cast<float4*>(pb + (size_t)row * N + col0) = t;
        } else {
            #pragma unroll
            for (int j = 0; j < 4; ++j) {
                const int n = col0 + j;
                if (n < N) pb[(size_t)row * N + n] = r[i][j];
            }
        }
    }
}

// ---------------------------------------------------------------------------
// Finalize, float4 path (requires N%4==0, zd%4==0): reduce partials over S,
// add coef-blended bias, ELU, append z.
// ---------------------------------------------------------------------------
__global__ __launch_bounds__(256) void moe_finalize4(
    const float4* __restrict__ part4,  // [S][B*N/4]
    const float* __restrict__ coef,    // [B,E]
    const float4* __restrict__ bias4,  // [E,N/4]
    const float4* __restrict__ z4,     // [B,ZD/4]
    float4* __restrict__ out4,         // [B,(N+zd)/4]
    int N, int S, int zd, int use_elu)
{
    const int stride4 = (N + zd) >> 2;
    const int idx = blockIdx.x * 256 + threadIdx.x;
    if (idx >= B * stride4) return;
    const int b  = idx / stride4;
    const int o4 = idx - b * stride4;
    const int N4 = N >> 2;

    if (o4 >= N4) {                    // z pass-through
        out4[idx] = z4[b * (ZD >> 2) + (o4 - N4)];
        return;
    }

    float4 v = {0.f, 0.f, 0.f, 0.f};
    for (int s = 0; s < S; ++s) {
        const float4 p = part4[(size_t)s * B * N4 + (size_t)b * N4 + o4];
        v.x += p.x; v.y += p.y; v.z += p.z; v.w += p.w;
    }
    #pragma unroll
    for (int e = 0; e < E; ++e) {
        const float c = coef[b * E + e];
        const float4 bb = bias4[e * N4 + o4];
        v.x = fmaf(c, bb.x, v.x);
        v.y = fmaf(c, bb.y, v.y);
        v.z = fmaf(c, bb.z, v.z);
        v.w = fmaf(c, bb.w, v.w);
    }
    if (use_elu) {
        if (v.x < 0.f) v.x = expm1f(v.x);
        if (v.y < 0.f) v.y = expm1f(v.y);
        if (v.z < 0.f) v.z = expm1f(v.z);
        if (v.w < 0.f) v.w = expm1f(v.w);
    }
    out4[idx] = v;
}

// Scalar finalize (L3: N=618).
__global__ __launch_bounds__(256) void moe_finalize(
    const float* __restrict__ part,
    const float* __restrict__ coef,
    const float* __restrict__ bias,
    const float* __restrict__ z,
    float* __restrict__ out,
    int N, int S, int zd, int use_elu)
{
    const int idx = blockIdx.x * 256 + threadIdx.x;
    const int ostride = N + zd;
    if (idx >= B * ostride) return;
    const int b = idx / ostride;
    const int o = idx - b * ostride;

    if (o >= N) { out[idx] = z[b * ZD + (o - N)]; return; }

    float v = 0.f;
    #pragma unroll 4
    for (int s = 0; s < S; ++s)
        v += part[(size_t)s * B * N + (size_t)b * N + o];
    #pragma unroll
    for (int e = 0; e < E; ++e)
        v = fmaf(coef[b * E + e], bias[e * N + o], v);
    if (use_elu && v < 0.f) v = expm1f(v);
    out[idx] = v;
}

extern "C" void kernel_launch(void* const* d_in, const int* in_sizes, int n_in,
                              void* d_out, int out_size, void* d_ws, size_t ws_size,
                              hipStream_t stream)
{
    const float* p_prev = (const float*)d_in[0];
    const float* coef   = (const float*)d_in[1];
    const float* z      = (const float*)d_in[2];
    const float* w1     = (const float*)d_in[3];
    const float* b1     = (const float*)d_in[4];
    const float* w2     = (const float*)d_in[5];
    const float* b2     = (const float*)d_in[6];
    const float* w3     = (const float*)d_in[7];
    const float* b3     = (const float*)d_in[8];
    float* out = (float*)d_out;

    // K-split tiering on ws_size (kchunk: mult of 8, divides K exactly)
    int kc1, kc23;
    {
        const size_t nf = ws_size / sizeof(float);
        const size_t xbuf = 2 * (size_t)B * K2;
        auto need = [&](int s1, int s23) {
            size_t a = (size_t)s1 * B * H_DIM;
            size_t c = (size_t)s23 * B * OUT_DIM;
            return (a > c ? a : c) + xbuf;
        };
        if (nf >= need(52, 34))      { kc1 = 32;  kc23 = 16; }
        else if (nf >= need(26, 17)) { kc1 = 64;  kc23 = 32; }
        else                         { kc1 = 128; kc23 = 32; }
    }
    const int S1  = IN_DIM / kc1;
    const int S23 = K2 / kc23;

    size_t maxPart = (size_t)S1 * B * H_DIM;
    {
        size_t p3 = (size_t)S23 * B * OUT_DIM;
        if (p3 > maxPart) maxPart = p3;
    }
    maxPart = (maxPart + 3) & ~(size_t)3;   // float4 alignment for x1/x2

    float* part = (float*)d_ws;
    float* x1   = part + maxPart;            // [B, 544] = act(512) ++ z(32)
    float* x2   = x1 + (size_t)B * K2;

    // L1: K=1664, N=512
    moe_gemm<true><<<dim3(16, S1), 256, 0, stream>>>(
        p_prev, coef, w1, part, IN_DIM, H_DIM, kc1);
    moe_finalize4<<<(B * (K2 / 4) + 255) / 256, 256, 0, stream>>>(
        (const float4*)part, coef, (const float4*)b1, (const float4*)z,
        (float4*)x1, H_DIM, S1, ZD, 1);

    // L2: K=544, N=512
    moe_gemm<true><<<dim3(16, S23), 256, 0, stream>>>(
        x1, coef, w2, part, K2, H_DIM, kc23);
    moe_finalize4<<<(B * (K2 / 4) + 255) / 256, 256, 0, stream>>>(
        (const float4*)part, coef, (const float4*)b2, (const float4*)z,
        (float4*)x2, H_DIM, S23, ZD, 1);

    // L3: K=544, N=618 (unaligned -> scalar w/partial path)
    moe_gemm<false><<<dim3((OUT_DIM + 31) / 32, S23), 256, 0, stream>>>(
        x2, coef, w3, part, K2, OUT_DIM, kc23);
    moe_finalize<<<(B * OUT_DIM + 255) / 256, 256, 0, stream>>>(
        part, coef, b3, nullptr, out, OUT_DIM, S23, 0, 0);
}

// Round 4
// 52.781 us; speedup vs baseline: 2.8197x; 2.8197x over previous
//
#include <hip/hip_runtime.h>
#include <math.h>

#define B 128
#define E 6
#define IN_DIM 1664
#define H_DIM 512
#define OUT_DIM 618
#define ZD 32
#define K2 (H_DIM + ZD)   // 544
#define KB1 52            // k32-blocks in L1 (1664/32)
#define KB23 17           // k32-blocks in L2/L3 (544/32)
#define NF12 32           // 16-col frags, N=512
#define NF3 40            // 16-col frags, N=618 padded to 640

typedef __attribute__((ext_vector_type(8))) short short8;
typedef __attribute__((ext_vector_type(4))) float f32x4;

union U128 { uint4 u4; short8 s8; ushort us[8]; };

__device__ __forceinline__ ushort f2bf(float f) {   // fp32 -> bf16 RNE
    uint u = __float_as_uint(f);
    u += 0x7fffu + ((u >> 16) & 1u);
    return (ushort)(u >> 16);
}

// ---------------------------------------------------------------------------
// prep_pass: build bf16 MFMA fragments in frag-major layout.
//   W_t[e][kb][nf][l][j]: lane l of frag = W[e][32kb+(l>>4)*8+j][16nf+(l&15)]
//   A  [e][kb][m ][l][j]: lane l of frag = coef[row,e]*x[row][32kb+(l>>4)*8+j],
//                         row = 16m+(l&15)
// Reads coalesced (per j: 16 lanes span 64B of a W row); 16B frag stores.
// ---------------------------------------------------------------------------
__device__ __forceinline__ void conv_w(const float* __restrict__ w,
                                       ushort* __restrict__ wt,
                                       int u, int KB, int NF, int K, int Nvalid, int N) {
    const int l = u & 63;
    int t = u >> 6;
    const int nf = t % NF; t /= NF;
    const int kb = t % KB; const int e = t / KB;
    const int n  = nf * 16 + (l & 15);
    const int k0 = kb * 32 + ((l >> 4) << 3);
    const float* src = w + ((size_t)e * K + k0) * N + n;
    U128 r;
    if (n < Nvalid) {
        #pragma unroll
        for (int j = 0; j < 8; ++j) r.us[j] = f2bf(src[(size_t)j * N]);
    } else {
        #pragma unroll
        for (int j = 0; j < 8; ++j) r.us[j] = 0;   // zero-pad cols >= 618 (L3)
    }
    *reinterpret_cast<uint4*>(wt + (size_t)u * 8) = r.u4;
}

__global__ __launch_bounds__(256) void prep_pass(
    const float* __restrict__ w1, const float* __restrict__ w2,
    const float* __restrict__ w3, const float* __restrict__ x,
    const float* __restrict__ coef,
    ushort* __restrict__ wt1, ushort* __restrict__ wt2,
    ushort* __restrict__ wt3, ushort* __restrict__ a1)
{
    const int idx = blockIdx.x * 256 + threadIdx.x;
    const int U0 = E * KB1 * NF12 * 64;          // 638976
    const int U1 = U0 + E * KB23 * NF12 * 64;    // 847872
    const int U2 = U1 + E * KB23 * NF3 * 64;     // 1108992
    if (idx < U0) {
        conv_w(w1, wt1, idx, KB1, NF12, IN_DIM, H_DIM, H_DIM);
    } else if (idx < U1) {
        conv_w(w2, wt2, idx - U0, KB23, NF12, K2, H_DIM, H_DIM);
    } else if (idx < U2) {
        conv_w(w3, wt3, idx - U1, KB23, NF3, K2, OUT_DIM, OUT_DIM);
    } else {
        const int u = idx - U2;                  // A1 frags: 159744 units
        const int l = u & 63;
        int t = u >> 6;
        const int m = t & 7; t >>= 3;
        const int kb = t % KB1; const int e = t / KB1;
        const int row = m * 16 + (l & 15);
        const int k0  = kb * 32 + ((l >> 4) << 3);
        const float c = coef[row * E + e];
        const float4 v0 = *reinterpret_cast<const float4*>(x + (size_t)row * IN_DIM + k0);
        const float4 v1 = *reinterpret_cast<const float4*>(x + (size_t)row * IN_DIM + k0 + 4);
        U128 r;
        r.us[0] = f2bf(v0.x * c); r.us[1] = f2bf(v0.y * c);
        r.us[2] = f2bf(v0.z * c); r.us[3] = f2bf(v0.w * c);
        r.us[4] = f2bf(v1.x * c); r.us[5] = f2bf(v1.y * c);
        r.us[6] = f2bf(v1.z * c); r.us[7] = f2bf(v1.w * c);
        *reinterpret_cast<uint4*>(a1 + (size_t)u * 8) = r.u4;
    }
}

// ---------------------------------------------------------------------------
// MFMA gemm, zero LDS, zero barriers. Block 256 = 4 waves; block tile
// 128 rows x 32 cols; wave tile 32x32 (2 m-frags x 2 n-frags). Per (e,kb):
// 4 coalesced dwordx4 frag loads + 4 mfma_f32_16x16x32_bf16. Split-K
// partials (non-atomic) indexed by blockIdx.y.
// ---------------------------------------------------------------------------
template<int KB, int KPB, int NF, int N>
__global__ __launch_bounds__(256) void moe_mfma_gemm(
    const uint4* __restrict__ afrag,   // [E][KB][8][64]
    const uint4* __restrict__ wfrag,   // [E][KB][NF][64]
    float* __restrict__ part)          // [S][B][N]
{
    const int l   = threadIdx.x & 63;
    const int wv  = threadIdx.x >> 6;
    const int nf0 = blockIdx.x * 2;
    const int kb0 = blockIdx.y * KPB;

    f32x4 acc00 = {0.f, 0.f, 0.f, 0.f};
    f32x4 acc01 = {0.f, 0.f, 0.f, 0.f};
    f32x4 acc10 = {0.f, 0.f, 0.f, 0.f};
    f32x4 acc11 = {0.f, 0.f, 0.f, 0.f};

    #pragma unroll
    for (int e = 0; e < E; ++e) {
        #pragma unroll
        for (int kbi = 0; kbi < KPB; ++kbi) {
            const size_t fb = (size_t)(e * KB + kb0 + kbi);
            U128 a0, a1, b0, b1;
            a0.u4 = afrag[(fb * 8 + 2 * wv    ) * 64 + l];
            a1.u4 = afrag[(fb * 8 + 2 * wv + 1) * 64 + l];
            b0.u4 = wfrag[(fb * NF + nf0    ) * 64 + l];
            b1.u4 = wfrag[(fb * NF + nf0 + 1) * 64 + l];
            acc00 = __builtin_amdgcn_mfma_f32_16x16x32_bf16(a0.s8, b0.s8, acc00, 0, 0, 0);
            acc01 = __builtin_amdgcn_mfma_f32_16x16x32_bf16(a0.s8, b1.s8, acc01, 0, 0, 0);
            acc10 = __builtin_amdgcn_mfma_f32_16x16x32_bf16(a1.s8, b0.s8, acc10, 0, 0, 0);
            acc11 = __builtin_amdgcn_mfma_f32_16x16x32_bf16(a1.s8, b1.s8, acc11, 0, 0, 0);
        }
    }

    // C/D layout (m89-verified): col = l&15, row = (l>>4)*4 + r
    float* pb = part + (size_t)blockIdx.y * B * N;
    const int colB = blockIdx.x * 32 + (l & 15);
    const int rsub = (l >> 4) << 2;
    #pragma unroll
    for (int mi = 0; mi < 2; ++mi) {
        const int row = wv * 32 + mi * 16 + rsub;
        const f32x4 c0 = mi ? acc10 : acc00;
        const f32x4 c1 = mi ? acc11 : acc01;
        if (colB < N) {
            #pragma unroll
            for (int r = 0; r < 4; ++r) pb[(size_t)(row + r) * N + colB] = c0[r];
        }
        if (colB + 16 < N) {
            #pragma unroll
            for (int r = 0; r < 4; ++r) pb[(size_t)(row + r) * N + colB + 16] = c1[r];
        }
    }
}

// ---------------------------------------------------------------------------
// finalize (L1/L2): reduce split-K partials + blended bias + ELU, then emit
// the NEXT layer's A-fragments (coef-folded bf16, incl. z columns) directly.
// Thread owns (b, 4 consecutive k) -> 6 x 8B frag stores.
// ---------------------------------------------------------------------------
template<int S>
__global__ __launch_bounds__(256) void moe_finalize_mid(
    const float* __restrict__ part,     // [S][B][H_DIM]
    const float* __restrict__ coef,     // [B][E]
    const float* __restrict__ bias,     // [E][H_DIM]
    const float* __restrict__ z,        // [B][ZD]
    ushort* __restrict__ anext)         // [E][KB23][8][64][8]
{
    const int idx = blockIdx.x * 256 + threadIdx.x;   // B*K2/4 = 17408
    if (idx >= B * (K2 / 4)) return;
    const int b  = idx / (K2 / 4);
    const int o4 = (idx % (K2 / 4)) * 4;

    float vx, vy, vz2, vw;
    if (o4 < H_DIM) {
        float s0 = 0.f, s1 = 0.f, s2 = 0.f, s3 = 0.f;
        #pragma unroll 4
        for (int s = 0; s < S; ++s) {
            const float4 p = *reinterpret_cast<const float4*>(
                part + ((size_t)s * B + b) * H_DIM + o4);
            s0 += p.x; s1 += p.y; s2 += p.z; s3 += p.w;
        }
        #pragma unroll
        for (int e = 0; e < E; ++e) {
            const float c = coef[b * E + e];
            const float4 bb = *reinterpret_cast<const float4*>(
                bias + (size_t)e * H_DIM + o4);
            s0 = fmaf(c, bb.x, s0); s1 = fmaf(c, bb.y, s1);
            s2 = fmaf(c, bb.z, s2); s3 = fmaf(c, bb.w, s3);
        }
        vx = s0 < 0.f ? expm1f(s0) : s0;
        vy = s1 < 0.f ? expm1f(s1) : s1;
        vz2 = s2 < 0.f ? expm1f(s2) : s2;
        vw = s3 < 0.f ? expm1f(s3) : s3;
    } else {
        const float4 zv = *reinterpret_cast<const float4*>(z + b * ZD + (o4 - H_DIM));
        vx = zv.x; vy = zv.y; vz2 = zv.z; vw = zv.w;
    }

    // frag coords for k = o4..o4+3 (all share one 8B-aligned slot)
    const int kb = o4 >> 5;
    const int l  = (((o4 >> 3) & 3) << 4) | (b & 15);
    const int j0 = o4 & 7;               // 0 or 4
    const int m  = b >> 4;
    #pragma unroll
    for (int e = 0; e < E; ++e) {
        const float c = coef[b * E + e];
        uint2 pk;
        pk.x = (uint)f2bf(vx * c) | ((uint)f2bf(vy * c) << 16);
        pk.y = (uint)f2bf(vz2 * c) | ((uint)f2bf(vw * c) << 16);
        *reinterpret_cast<uint2*>(
            anext + ((((size_t)e * KB23 + kb) * 8 + m) * 64 + l) * 8 + j0) = pk;
    }
}

// finalize (L3): partial reduce + blended bias, no activation, to d_out.
template<int S>
__global__ __launch_bounds__(256) void moe_finalize_last(
    const float* __restrict__ part,     // [S][B][OUT_DIM]
    const float* __restrict__ coef,
    const float* __restrict__ bias,     // [E][OUT_DIM]
    float* __restrict__ out)            // [B][OUT_DIM]
{
    const int idx = blockIdx.x * 256 + threadIdx.x;
    if (idx >= B * OUT_DIM) return;
    const int b = idx / OUT_DIM;
    const int o = idx - b * OUT_DIM;
    float v = 0.f;
    #pragma unroll 4
    for (int s = 0; s < S; ++s) v += part[((size_t)s * B + b) * OUT_DIM + o];
    #pragma unroll
    for (int e = 0; e < E; ++e)
        v = fmaf(coef[b * E + e], bias[(size_t)e * OUT_DIM + o], v);
    out[idx] = v;
}

extern "C" void kernel_launch(void* const* d_in, const int* in_sizes, int n_in,
                              void* d_out, int out_size, void* d_ws, size_t ws_size,
                              hipStream_t stream)
{
    const float* p_prev = (const float*)d_in[0];
    const float* coef   = (const float*)d_in[1];
    const float* z      = (const float*)d_in[2];
    const float* w1     = (const float*)d_in[3];
    const float* b1     = (const float*)d_in[4];
    const float* w2     = (const float*)d_in[5];
    const float* b2     = (const float*)d_in[6];
    const float* w3     = (const float*)d_in[7];
    const float* b3     = (const float*)d_in[8];
    float* out = (float*)d_out;

    // ws layout (bytes); total ~28.8 MB (ws is ~268 MB per harness fill)
    char* p = (char*)d_ws;
    ushort* wt1 = (ushort*)p; p += (size_t)E * KB1  * NF12 * 64 * 16;  // 10,223,616
    ushort* wt2 = (ushort*)p; p += (size_t)E * KB23 * NF12 * 64 * 16;  //  3,342,336
    ushort* wt3 = (ushort*)p; p += (size_t)E * KB23 * NF3  * 64 * 16;  //  4,177,920
    ushort* a1  = (ushort*)p; p += (size_t)E * KB1  * 8    * 64 * 16;  //  2,555,904
    ushort* a2  = (ushort*)p; p += (size_t)E * KB23 * 8    * 64 * 16;  //    835,584
    ushort* a3  = (ushort*)p; p += (size_t)E * KB23 * 8    * 64 * 16;  //    835,584
    float*  part = (float*)p;                                          //  6,815,744 max

    // 1) all W transposes/conversions + L1 A-fragments (1,268,736 units)
    prep_pass<<<4956, 256, 0, stream>>>(w1, w2, w3, p_prev, coef,
                                        wt1, wt2, wt3, a1);

    // 2) L1: grid 16 n-tiles x 26 splits (kc=64)
    moe_mfma_gemm<KB1, 2, NF12, H_DIM><<<dim3(16, 26), 256, 0, stream>>>(
        (const uint4*)a1, (const uint4*)wt1, part);
    moe_finalize_mid<26><<<68, 256, 0, stream>>>(part, coef, b1, z, a2);

    // 3) L2: grid 16 x 17 (kc=32)
    moe_mfma_gemm<KB23, 1, NF12, H_DIM><<<dim3(16, 17), 256, 0, stream>>>(
        (const uint4*)a2, (const uint4*)wt2, part);
    moe_finalize_mid<17><<<68, 256, 0, stream>>>(part, coef, b2, z, a3);

    // 4) L3: grid 20 x 17 (kc=32), cols 618..639 zero-padded in wt3
    moe_mfma_gemm<KB23, 1, NF3, OUT_DIM><<<dim3(20, 17), 256, 0, stream>>>(
        (const uint4*)a3, (const uint4*)wt3, part);
    moe_finalize_last<17><<<(B * OUT_DIM + 255) / 256, 256, 0, stream>>>(
        part, coef, b3, out);
}